// Round 1
// baseline (264.353 us; speedup 1.0000x reference)
//
#include <hip/hip_runtime.h>
#include <stdint.h>

typedef __attribute__((__ext_vector_type__(8))) __bf16 bf16x8;
typedef __attribute__((__ext_vector_type__(4))) float  f32x4;

// ---- workspace layout (bytes) ----
#define XT_OFF    0ul          // 16*64*64*256 bf16 = 33,554,432
#define WT_OFF    33554432ul   // 256*9*256 bf16    =  1,179,648
#define BEFF_OFF  34734080ul   // 256 f32
#define SCALE_OFF 34735104ul   // 256 f32
#define SHIFT_OFF 34736128ul   // 256 f32
#define ZERO_OFF  34737152ul   // 256 B zeros

__device__ inline void gload_lds16(const void* g, void* l) {
  __builtin_amdgcn_global_load_lds((const __attribute__((address_space(1))) void*)g,
                                   (__attribute__((address_space(3))) void*)l,
                                   16, 0, 0);
}

// K1: W_t[co][tap][ci] = alpha/16 * sum_{r,o} weight_all[r*256+co][o*256+ci][tap]
__global__ void k_wred(const float* __restrict__ w, const float* __restrict__ bias,
                       const float* __restrict__ alpha_p, __bf16* __restrict__ Wt,
                       float* __restrict__ beff, float* __restrict__ zerob) {
  int idx = blockIdx.x * 256 + threadIdx.x;   // < 589824
  int ci  = idx & 255;
  int ct  = idx >> 8;                         // co*9 + tap
  int co  = ct / 9;
  int tap = ct - co * 9;
  float s = 0.f;
#pragma unroll
  for (int r = 0; r < 2; ++r)
#pragma unroll
    for (int o = 0; o < 8; ++o)
      s += w[((size_t)(r * 256 + co) * 2048 + (size_t)(o * 256 + ci)) * 9 + tap];
  float sc = alpha_p[0] * 0.0625f;            // alpha / (NORI*NROT)
  Wt[idx] = (__bf16)(s * sc);
  if (tap == 0 && ci == 0)
    beff[co] = (bias[co] + bias[256 + co]) * 8.0f * sc;
  if (idx < 64) zerob[idx] = 0.0f;
}

// K1b: x[b][ci][h][w] f32 -> xT[b][h][w][ci] bf16  (LDS-tiled transpose)
__global__ void k_xpose(const float* __restrict__ x, __bf16* __restrict__ xT) {
  __shared__ __bf16 lds[64 * 258];
  int bh = blockIdx.x;          // 16*64
  int b = bh >> 6, h = bh & 63;
  int t = threadIdx.x;          // 256
  int w = t & 63, cg = t >> 6;
  const float* xb = x + ((size_t)b * 16384 + h) * 64;   // + ci*4096 + w
#pragma unroll 4
  for (int cb = 0; cb < 256; cb += 4) {
    int ci = cb + cg;
    lds[w * 258 + ci] = (__bf16)xb[(size_t)ci * 4096 + w];
  }
  __syncthreads();
  const uint32_t* l32 = (const uint32_t*)lds;
  uint32_t* o32 = (uint32_t*)(xT + ((size_t)b * 64 + h) * 64 * 256);
  int c2 = t & 127, wg = t >> 7;              // 2 w per iter
  for (int w0 = 0; w0 < 64; w0 += 2) {
    int ww = w0 + wg;
    o32[ww * 128 + c2] = l32[ww * 129 + c2];
  }
}

// K2: implicit-GEMM conv + residual.  out = x + conv_scaled + beff
#define SLAB 33792  // 4 rows * 66 cols * 64 ci * 2B

__global__ __launch_bounds__(512) void k_conv(
    const float* __restrict__ x, const __bf16* __restrict__ xT,
    const __bf16* __restrict__ Wt, const float* __restrict__ beff,
    const __bf16* __restrict__ zerob, float* __restrict__ out)
{
  __shared__ __align__(16) char lds[2 * SLAB];
  const int bb   = blockIdx.x >> 5;
  const int ho0  = (blockIdx.x & 31) << 1;   // 2 output rows per block
  const int tid  = threadIdx.x;
  const int lane = tid & 63;
  const int wid  = tid >> 6;                 // 8 waves: 2 (m) x 4 (co)
  const int wr   = wid >> 2;
  const int wc   = wid & 3;

  f32x4 acc[4][4];
#pragma unroll
  for (int i = 0; i < 4; ++i)
#pragma unroll
    for (int j = 0; j < 4; ++j)
#pragma unroll
      for (int r = 0; r < 4; ++r) acc[i][j][r] = 0.f;

  const char* zb = (const char*)zerob;

  // stage ci-slice s into buffer bi: logical slab[r][c][ci] (r=4, c=66, ci=64 bf16)
  // phys 16B-slot swizzle: slot = k ^ (pos&7); dest linear => inverse-swizzle source.
  auto stage = [&](int bi, int s) {
    char* buf = lds + bi * SLAB;
    const int ci0 = s << 6;
    for (int t = wid; t < 33; t += 8) {        // 33 wave-instrs, 8 chunks each
      const int ch = (t << 3) + (lane >> 3);   // pos = r*66+c, 0..263
      const int r  = ch / 66;
      const int c  = ch - r * 66;
      const int ir = ho0 - 1 + r;              // image row
      const int ic = c - 1;                    // image col
      const int k  = (lane & 7) ^ (ch & 7);    // logical 16B slot
      const char* src;
      if (ir >= 0 && ir < 64 && ic >= 0 && ic < 64)
        src = (const char*)(xT + ((((size_t)bb << 6) + ir) * 64 + ic) * 256 + ci0 + (k << 3));
      else
        src = zb + (k << 4);
      gload_lds16(src, buf + (t << 10));       // wave-uniform LDS base
    }
  };

  stage(0, 0);
  __syncthreads();

  for (int s = 0; s < 4; ++s) {                // 4 ci-steps of 64
    if (s < 3) stage((s + 1) & 1, s + 1);
    const char* sl  = lds + (s & 1) * SLAB;
    const int   ci0 = s << 6;
    for (int tap = 0; tap < 9; ++tap) {
      const int dh = tap / 3;
      const int dw = tap - dh * 3;
      const int srow = wr + dh;
#pragma unroll
      for (int kk = 0; kk < 2; ++kk) {
        const int ci_off = (kk << 5) + ((lane >> 4) << 3);
        bf16x8 av[4];
#pragma unroll
        for (int i = 0; i < 4; ++i) {
          const int pos = srow * 66 + (i << 4) + (lane & 15) + dw;
          const int off = ((pos << 7) + (ci_off << 1)) ^ ((pos & 7) << 4);
          av[i] = *(const bf16x8*)(sl + off);
        }
#pragma unroll
        for (int j = 0; j < 4; ++j) {
          const int co = (wc << 6) + (j << 4) + (lane & 15);
          const bf16x8 bv = *(const bf16x8*)(Wt + (size_t)co * 2304 + tap * 256 + ci0 + ci_off);
#pragma unroll
          for (int i = 0; i < 4; ++i)
            acc[i][j] = __builtin_amdgcn_mfma_f32_16x16x32_bf16(av[i], bv, acc[i][j], 0, 0, 0);
        }
      }
    }
    __syncthreads();
  }

  // epilogue: per-wave LDS transpose so global IO is coalesced along w
  float* sw = (float*)lds + wid * (16 * 65);
  const int ho = ho0 + wr;
#pragma unroll
  for (int j = 0; j < 4; ++j) {
#pragma unroll
    for (int i = 0; i < 4; ++i)
#pragma unroll
      for (int r = 0; r < 4; ++r)
        sw[(lane & 15) * 65 + (i << 4) + ((lane >> 4) << 2) + r] = acc[i][j][r];
    for (int cc = 0; cc < 16; ++cc) {
      const int co = (wc << 6) + (j << 4) + cc;
      const float conv = sw[cc * 65 + lane];
      const size_t oi = ((((size_t)bb << 8) + (size_t)co) << 12) + (ho << 6) + lane;
      out[oi] = x[oi] + conv + beff[co];
    }
  }
}

// K2b: per-channel batch stats -> scale/shift
__global__ void k_stats(const float* __restrict__ out, const float* __restrict__ gamma,
                        const float* __restrict__ beta, float* __restrict__ scale,
                        float* __restrict__ shift) {
  int co = blockIdx.x, t = threadIdx.x;
  float s = 0.f, ss = 0.f;
  for (int b = 0; b < 16; ++b) {
    const float4* p = (const float4*)(out + (((size_t)b * 256 + co) << 12));
    for (int q = t; q < 1024; q += 256) {
      float4 v = p[q];
      s  += v.x + v.y + v.z + v.w;
      ss += v.x * v.x + v.y * v.y + v.z * v.z + v.w * v.w;
    }
  }
  __shared__ float red[2][8];
  int lane = t & 63, wv = t >> 6;
  for (int o = 32; o; o >>= 1) { s += __shfl_down(s, o); ss += __shfl_down(ss, o); }
  if (lane == 0) { red[0][wv] = s; red[1][wv] = ss; }
  __syncthreads();
  if (t == 0) {
    float S = 0.f, SS = 0.f;
    for (int i = 0; i < 4; ++i) { S += red[0][i]; SS += red[1][i]; }
    float mean = S * (1.f / 65536.f);
    float var  = SS * (1.f / 65536.f) - mean * mean;
    float inv  = rsqrtf(var + 1e-5f);
    float sc   = gamma[co] * inv;
    scale[co] = sc;
    shift[co] = beta[co] - mean * sc;
  }
}

// K3: in-place BN apply
__global__ void k_apply(float* __restrict__ out, const float* __restrict__ scale,
                        const float* __restrict__ shift) {
  size_t i = (size_t)blockIdx.x * 256 + threadIdx.x;   // float4 index
  float4* p = (float4*)out;
  float4 v = p[i];
  int co = (int)((i >> 10) & 255);
  float sc = scale[co], sh = shift[co];
  v.x = v.x * sc + sh; v.y = v.y * sc + sh; v.z = v.z * sc + sh; v.w = v.w * sc + sh;
  p[i] = v;
}

extern "C" void kernel_launch(void* const* d_in, const int* in_sizes, int n_in,
                              void* d_out, int out_size, void* d_ws, size_t ws_size,
                              hipStream_t stream) {
  const float* x     = (const float*)d_in[0];
  const float* wall  = (const float*)d_in[1];
  const float* bias  = (const float*)d_in[2];
  const float* alpha = (const float*)d_in[3];
  const float* gamma = (const float*)d_in[4];
  const float* beta  = (const float*)d_in[5];
  float* out = (float*)d_out;

  char* ws = (char*)d_ws;
  __bf16* xT    = (__bf16*)(ws + XT_OFF);
  __bf16* Wt    = (__bf16*)(ws + WT_OFF);
  float*  beff  = (float*)(ws + BEFF_OFF);
  float*  scale = (float*)(ws + SCALE_OFF);
  float*  shift = (float*)(ws + SHIFT_OFF);
  float*  zerob = (float*)(ws + ZERO_OFF);

  k_wred<<<2304, 256, 0, stream>>>(wall, bias, alpha, Wt, beff, zerob);
  k_xpose<<<1024, 256, 0, stream>>>(x, xT);
  k_conv<<<512, 512, 0, stream>>>(x, xT, Wt, beff, (const __bf16*)zerob, out);
  k_stats<<<256, 256, 0, stream>>>(out, gamma, beta, scale, shift);
  k_apply<<<16384, 256, 0, stream>>>(out, scale, shift);
}

// Round 2
// 185.999 us; speedup vs baseline: 1.4213x; 1.4213x over previous
//
#include <hip/hip_runtime.h>
#include <stdint.h>

typedef __attribute__((__ext_vector_type__(8))) __bf16 bf16x8;
typedef __attribute__((__ext_vector_type__(4))) float  f32x4;

// ---- workspace layout (bytes) ----
#define XT_OFF    0ul          // 16*64*64*256 bf16 = 33,554,432
#define WT_OFF    33554432ul   // 256*9*256 bf16    =  1,179,648
#define BEFF_OFF  34734080ul   // 256 f32
#define SCALE_OFF 34735104ul   // 256 f32
#define SHIFT_OFF 34736128ul   // 256 f32
#define ZERO_OFF  34737152ul   // 256 B zeros

__device__ inline void gload_lds16(const void* g, void* l) {
  __builtin_amdgcn_global_load_lds((const __attribute__((address_space(1))) void*)g,
                                   (__attribute__((address_space(3))) void*)l,
                                   16, 0, 0);
}

// K1: W_t[co][tap][ci] = alpha/16 * sum_{r,o} weight_all[r*256+co][o*256+ci][tap]
__global__ void k_wred(const float* __restrict__ w, const float* __restrict__ bias,
                       const float* __restrict__ alpha_p, __bf16* __restrict__ Wt,
                       float* __restrict__ beff, float* __restrict__ zerob) {
  int idx = blockIdx.x * 256 + threadIdx.x;   // < 589824
  int ci  = idx & 255;
  int ct  = idx >> 8;                         // co*9 + tap
  int co  = ct / 9;
  int tap = ct - co * 9;
  float s = 0.f;
#pragma unroll
  for (int r = 0; r < 2; ++r)
#pragma unroll
    for (int o = 0; o < 8; ++o)
      s += w[((size_t)(r * 256 + co) * 2048 + (size_t)(o * 256 + ci)) * 9 + tap];
  float sc = alpha_p[0] * 0.0625f;            // alpha / (NORI*NROT)
  Wt[idx] = (__bf16)(s * sc);
  if (tap == 0 && ci == 0)
    beff[co] = (bias[co] + bias[256 + co]) * 8.0f * sc;
  if (idx < 64) zerob[idx] = 0.0f;
}

// K1b: x[b][ci][h][w] f32 -> xT[b][h][w][ci] bf16  (LDS-tiled transpose)
__global__ void k_xpose(const float* __restrict__ x, __bf16* __restrict__ xT) {
  __shared__ __bf16 lds[64 * 258];
  int bh = blockIdx.x;          // 16*64
  int b = bh >> 6, h = bh & 63;
  int t = threadIdx.x;          // 256
  int w = t & 63, cg = t >> 6;
  const float* xb = x + ((size_t)b * 16384 + h) * 64;   // + ci*4096 + w
#pragma unroll 4
  for (int cb = 0; cb < 256; cb += 4) {
    int ci = cb + cg;
    lds[w * 258 + ci] = (__bf16)xb[(size_t)ci * 4096 + w];
  }
  __syncthreads();
  const uint32_t* l32 = (const uint32_t*)lds;
  uint32_t* o32 = (uint32_t*)(xT + ((size_t)b * 64 + h) * 64 * 256);
  int c2 = t & 127, wg = t >> 7;              // 2 w per iter
  for (int w0 = 0; w0 < 64; w0 += 2) {
    int ww = w0 + wg;
    o32[ww * 128 + c2] = l32[ww * 129 + c2];
  }
}

// K2: implicit-GEMM conv + residual.  out = x + conv_scaled + beff
// 256 blocks (b 16 x rowgroup 16), 512 threads (8 waves = 2m x 4n).
// BM=256 (4 output rows x 64 w), N=256 co, K = s(4 ci64-blocks) x tap(9).
// A-slab: 6 rows x 66 cols x 64 ci bf16, staged per s (reused by 9 taps),
//   single-buffered (re-stage barrier at s boundary).
// B-tile: 256 co x 64 ci bf16 = 32KB, double-buffered per (s,tap) phase.
// 2-phase schedule: STAGE(next B) -> ds_read+MFMA(cur) -> vmcnt0+barrier.
#define A_BYTES 51200            // 50 * 1024 (396 pos * 128B, padded)
#define B_BYTES 32768

__global__ __launch_bounds__(512) void k_conv(
    const float* __restrict__ x, const __bf16* __restrict__ xT,
    const __bf16* __restrict__ Wt, const float* __restrict__ beff,
    const __bf16* __restrict__ zerob, float* __restrict__ out)
{
  __shared__ __align__(16) char lds[A_BYTES + 2 * B_BYTES];   // 116736 B
  const int bb   = blockIdx.x >> 4;
  const int ho0  = (blockIdx.x & 15) << 2;   // 4 output rows per block
  const int tid  = threadIdx.x;
  const int lane = tid & 63;
  const int wid  = tid >> 6;                 // 8 waves: 2 (m) x 4 (co)
  const int wr   = wid >> 2;                 // m half: rows ho0+wr*2+{0,1}
  const int wc   = wid & 3;                  // co quarter (64)

  f32x4 acc[8][4];
#pragma unroll
  for (int i = 0; i < 8; ++i)
#pragma unroll
    for (int j = 0; j < 4; ++j)
#pragma unroll
      for (int r = 0; r < 4; ++r) acc[i][j][r] = 0.f;

  const char* zb = (const char*)zerob;

  // ---- stage A slab for ci-block s: slab[r=6][c=66][ci=64] bf16, 128B/pos,
  // 16B-slot swizzle: phys_slot = logical_slot ^ (pos&7); linear LDS dest +
  // inverse-swizzled global source (G21).
  auto stageA = [&](int s) {
    const int ci0 = s << 6;
    for (int t = wid; t < 50; t += 8) {
      const int ch = (t << 3) + (lane >> 3);   // pos = r*66+c, 0..399
      const int r  = ch / 66;
      const int c  = ch - r * 66;
      const int ir = ho0 - 1 + r;              // image row
      const int ic = c - 1;                    // image col
      const int k  = (lane & 7) ^ (ch & 7);    // logical 16B slot (8 ci elems)
      const char* src;
      if (ch < 396 && ir >= 0 && ir < 64 && ic >= 0 && ic < 64)
        src = (const char*)(xT + ((((size_t)bb << 6) + ir) * 64 + ic) * 256 + ci0 + (k << 3));
      else
        src = zb + (k << 4);
      gload_lds16(src, lds + (t << 10));
    }
  };

  // ---- stage B tile for (s,tap) into buffer bi: Btile[co=256][ci=64] bf16,
  // 128B/co, same slot swizzle keyed on co.
  auto stageB = [&](int bi, int s, int tap) {
    char* buf = lds + A_BYTES + bi * B_BYTES;
    for (int t = wid; t < 32; t += 8) {
      const int co = (t << 3) + (lane >> 3);
      const int k  = (lane & 7) ^ (co & 7);
      const char* src = (const char*)Wt + (((size_t)co * 2304 + tap * 256 + (s << 6)) << 1) + (k << 4);
      gload_lds16(src, buf + (t << 10));
    }
  };

  stageA(0);
  stageB(0, 0, 0);
  __syncthreads();                             // vmcnt(0) drain by compiler

  int pb = 0;
  for (int s = 0; s < 4; ++s) {
    for (int tap = 0; tap < 9; ++tap) {
      {
        const int np = s * 9 + tap + 1;
        if (np < 36) stageB(pb ^ 1, np / 9, np % 9);
      }
      const int dh = tap / 3;
      const int dw = tap - dh * 3;
      const char* Bb = lds + A_BYTES + pb * B_BYTES;
#pragma unroll
      for (int kk = 0; kk < 2; ++kk) {
        const int ci_off = (kk << 5) + ((lane >> 4) << 3);
        bf16x8 av[8];
#pragma unroll
        for (int i = 0; i < 8; ++i) {
          const int pos = ((wr << 1) + (i >> 2) + dh) * 66 + ((i & 3) << 4) + (lane & 15) + dw;
          const int off = ((pos << 7) + (ci_off << 1)) ^ ((pos & 7) << 4);
          av[i] = *(const bf16x8*)(lds + off);
        }
#pragma unroll
        for (int j = 0; j < 4; ++j) {
          const int co   = (wc << 6) + (j << 4) + (lane & 15);
          const int boff = ((co << 7) + (ci_off << 1)) ^ ((co & 7) << 4);
          const bf16x8 bv = *(const bf16x8*)(Bb + boff);
#pragma unroll
          for (int i = 0; i < 8; ++i)
            acc[i][j] = __builtin_amdgcn_mfma_f32_16x16x32_bf16(av[i], bv, acc[i][j], 0, 0, 0);
        }
      }
      __syncthreads();                         // drains this phase's staging
      if (tap == 8 && s < 3) {                 // re-stage A (single-buffered)
        stageA(s + 1);
        __syncthreads();
      }
      pb ^= 1;
    }
  }

  // ---- epilogue: per-wave LDS transpose so global IO is coalesced along w
  float* sw = (float*)lds + wid * 2064;        // 16 co x 129 m floats
  const int cl = lane & 15, ch4 = (lane >> 4) << 2;
#pragma unroll
  for (int j = 0; j < 4; ++j) {
    asm volatile("s_waitcnt lgkmcnt(0)" ::: "memory");  // prev j reads done
#pragma unroll
    for (int i = 0; i < 8; ++i)
#pragma unroll
      for (int r = 0; r < 4; ++r)
        sw[cl * 129 + (i << 4) + ch4 + r] = acc[i][j][r];
    for (int cc = 0; cc < 16; ++cc) {
      const int co = (wc << 6) + (j << 4) + cc;
      const float be = beff[co];
#pragma unroll
      for (int half = 0; half < 2; ++half) {
        const float conv = sw[cc * 129 + (half << 6) + lane];
        const int ho = ho0 + (wr << 1) + half;
        const size_t oi = ((((size_t)bb << 8) + (size_t)co) << 12) + (ho << 6) + lane;
        out[oi] = x[oi] + conv + be;
      }
    }
  }
}

// K2b: per-channel batch stats -> scale/shift
__global__ void k_stats(const float* __restrict__ out, const float* __restrict__ gamma,
                        const float* __restrict__ beta, float* __restrict__ scale,
                        float* __restrict__ shift) {
  int co = blockIdx.x, t = threadIdx.x;
  float s = 0.f, ss = 0.f;
  for (int b = 0; b < 16; ++b) {
    const float4* p = (const float4*)(out + (((size_t)b * 256 + co) << 12));
    for (int q = t; q < 1024; q += 256) {
      float4 v = p[q];
      s  += v.x + v.y + v.z + v.w;
      ss += v.x * v.x + v.y * v.y + v.z * v.z + v.w * v.w;
    }
  }
  __shared__ float red[2][8];
  int lane = t & 63, wv = t >> 6;
  for (int o = 32; o; o >>= 1) { s += __shfl_down(s, o); ss += __shfl_down(ss, o); }
  if (lane == 0) { red[0][wv] = s; red[1][wv] = ss; }
  __syncthreads();
  if (t == 0) {
    float S = 0.f, SS = 0.f;
    for (int i = 0; i < 4; ++i) { S += red[0][i]; SS += red[1][i]; }
    float mean = S * (1.f / 65536.f);
    float var  = SS * (1.f / 65536.f) - mean * mean;
    float inv  = rsqrtf(var + 1e-5f);
    float sc   = gamma[co] * inv;
    scale[co] = sc;
    shift[co] = beta[co] - mean * sc;
  }
}

// K3: in-place BN apply
__global__ void k_apply(float* __restrict__ out, const float* __restrict__ scale,
                        const float* __restrict__ shift) {
  size_t i = (size_t)blockIdx.x * 256 + threadIdx.x;   // float4 index
  float4* p = (float4*)out;
  float4 v = p[i];
  int co = (int)((i >> 10) & 255);
  float sc = scale[co], sh = shift[co];
  v.x = v.x * sc + sh; v.y = v.y * sc + sh; v.z = v.z * sc + sh; v.w = v.w * sc + sh;
  p[i] = v;
}

extern "C" void kernel_launch(void* const* d_in, const int* in_sizes, int n_in,
                              void* d_out, int out_size, void* d_ws, size_t ws_size,
                              hipStream_t stream) {
  const float* x     = (const float*)d_in[0];
  const float* wall  = (const float*)d_in[1];
  const float* bias  = (const float*)d_in[2];
  const float* alpha = (const float*)d_in[3];
  const float* gamma = (const float*)d_in[4];
  const float* beta  = (const float*)d_in[5];
  float* out = (float*)d_out;

  char* ws = (char*)d_ws;
  __bf16* xT    = (__bf16*)(ws + XT_OFF);
  __bf16* Wt    = (__bf16*)(ws + WT_OFF);
  float*  beff  = (float*)(ws + BEFF_OFF);
  float*  scale = (float*)(ws + SCALE_OFF);
  float*  shift = (float*)(ws + SHIFT_OFF);
  float*  zerob = (float*)(ws + ZERO_OFF);

  k_wred<<<2304, 256, 0, stream>>>(wall, bias, alpha, Wt, beff, zerob);
  k_xpose<<<1024, 256, 0, stream>>>(x, xT);
  k_conv<<<256, 512, 0, stream>>>(x, xT, Wt, beff, (const __bf16*)zerob, out);
  k_stats<<<256, 256, 0, stream>>>(out, gamma, beta, scale, shift);
  k_apply<<<16384, 256, 0, stream>>>(out, scale, shift);
}

// Round 3
// 153.962 us; speedup vs baseline: 1.7170x; 1.2081x over previous
//
#include <hip/hip_runtime.h>
#include <stdint.h>

typedef __attribute__((__ext_vector_type__(8))) __bf16 bf16x8;
typedef __attribute__((__ext_vector_type__(4))) float  f32x4;

// ---- workspace layout (bytes) ----
#define XT_OFF    0ul          // 16*64*64*256 bf16 = 33,554,432
#define WT_OFF    33554432ul   // 256*9*256 bf16    =  1,179,648
#define BEFF_OFF  34734080ul   // 256 f32
#define SCALE_OFF 34735104ul   // 256 f32
#define SHIFT_OFF 34736128ul   // 256 f32
#define ZERO_OFF  34737152ul   // 256 B zeros
#define STATS_OFF 34737408ul   // 512 f32 (sum, sumsq per channel)

__device__ inline void gload_lds16(const void* g, void* l) {
  __builtin_amdgcn_global_load_lds((const __attribute__((address_space(1))) void*)g,
                                   (__attribute__((address_space(3))) void*)l,
                                   16, 0, 0);
}

// K1: W_t[co][tap][ci] = alpha/16 * sum_{r,o} weight_all[r*256+co][o*256+ci][tap]
// thread=(co=blockIdx,ci=threadIdx); 9 taps in regs; reads are contiguous 36B/lane.
__global__ void k_wred(const float* __restrict__ w, const float* __restrict__ bias,
                       const float* __restrict__ alpha_p, __bf16* __restrict__ Wt,
                       float* __restrict__ beff, float* __restrict__ zerob,
                       float* __restrict__ statsG) {
  const int co = blockIdx.x;    // 256
  const int ci = threadIdx.x;   // 256
  float a[9];
#pragma unroll
  for (int t = 0; t < 9; ++t) a[t] = 0.f;
#pragma unroll
  for (int r = 0; r < 2; ++r)
#pragma unroll
    for (int o = 0; o < 8; ++o) {
      const float* p = w + ((size_t)(r * 256 + co) * 2048 + (size_t)(o * 256 + ci)) * 9;
#pragma unroll
      for (int t = 0; t < 9; ++t) a[t] += p[t];
    }
  const float sc = alpha_p[0] * 0.0625f;      // alpha / (NORI*NROT)
#pragma unroll
  for (int t = 0; t < 9; ++t)
    Wt[((size_t)co * 9 + t) * 256 + ci] = (__bf16)(a[t] * sc);
  if (ci == 0) beff[co] = (bias[co] + bias[256 + co]) * 8.0f * sc;
  if (blockIdx.x == 0) {
    statsG[ci] = 0.f; statsG[256 + ci] = 0.f;
    if (ci < 64) zerob[ci] = 0.f;
  }
}

// K1b: x[b][ci][h][w] f32 -> xT[b][h][w][ci] bf16  (LDS-tiled transpose)
__global__ void k_xpose(const float* __restrict__ x, __bf16* __restrict__ xT) {
  __shared__ __bf16 lds[64 * 258];
  int bh = blockIdx.x;          // 16*64
  int b = bh >> 6, h = bh & 63;
  int t = threadIdx.x;          // 256
  int w = t & 63, cg = t >> 6;
  const float* xb = x + ((size_t)b * 16384 + h) * 64;   // + ci*4096 + w
#pragma unroll 4
  for (int cb = 0; cb < 256; cb += 4) {
    int ci = cb + cg;
    lds[w * 258 + ci] = (__bf16)xb[(size_t)ci * 4096 + w];
  }
  __syncthreads();
  const uint32_t* l32 = (const uint32_t*)lds;
  uint32_t* o32 = (uint32_t*)(xT + ((size_t)b * 64 + h) * 64 * 256);
  int c2 = t & 127, wg = t >> 7;              // 2 w per iter
  for (int w0 = 0; w0 < 64; w0 += 2) {
    int ww = w0 + wg;
    o32[ww * 128 + c2] = l32[ww * 129 + c2];
  }
}

// K2: implicit-GEMM conv + residual + fused BN stats.
// 256 blocks (b 16 x rowgroup 16), 512 threads (8 waves = 2m x 4n).
// BM=256 (4 out rows x 64 w), N=256 co, 36 phases = s(4 ci64) x tap(9), K=64/phase.
// Counted-vmcnt 2-barrier schedule (T4): per phase
//   barrier(A); stageB(next); vmcnt(4); barrier(B); ds_read+MFMA(setprio).
// A slab single-buffered, restaged after a post-MFMA barrier at s boundaries;
// its loads are drained by the NEXT phase's vmcnt(4) (counted waits are
// oldest-first, so the constant 4 = next-B loads works for mixed counts).
#define A_BYTES 51200            // 50 chunks * 1024 (396 pos * 128B, padded)
#define B_BYTES 32768

__global__ __launch_bounds__(512) void k_conv(
    const float* __restrict__ x, const __bf16* __restrict__ xT,
    const __bf16* __restrict__ Wt, const float* __restrict__ beff,
    const __bf16* __restrict__ zerob, float* __restrict__ out,
    float* __restrict__ statsG)
{
  __shared__ __align__(16) char lds[A_BYTES + 2 * B_BYTES];   // 116736 B
  const int bb   = blockIdx.x >> 4;
  const int ho0  = (blockIdx.x & 15) << 2;   // 4 output rows per block
  const int tid  = threadIdx.x;
  const int lane = tid & 63;
  const int wid  = tid >> 6;                 // 8 waves: 2 (m) x 4 (co)
  const int wr   = wid >> 2;                 // m half: rows ho0+wr*2+{0,1}
  const int wc   = wid & 3;                  // co quarter (64)

  f32x4 acc[8][4];
#pragma unroll
  for (int i = 0; i < 8; ++i)
#pragma unroll
    for (int j = 0; j < 4; ++j)
#pragma unroll
      for (int r = 0; r < 4; ++r) acc[i][j][r] = 0.f;

  const char* zb = (const char*)zerob;

  // hoisted B ds_read byte offsets: constant across phases
  int boff[4][2];
#pragma unroll
  for (int j = 0; j < 4; ++j)
#pragma unroll
    for (int kk = 0; kk < 2; ++kk) {
      const int co     = (wc << 6) + (j << 4) + (lane & 15);
      const int ci_off = (kk << 5) + ((lane >> 4) << 3);
      boff[j][kk] = ((co << 7) + (ci_off << 1)) ^ ((co & 7) << 4);
    }
  // hoisted B stage per-lane source offset (bytes): co = t*8 + (lane>>3)
  const int bl = lane >> 3;
  const size_t bsrcLane = (size_t)bl * 4608 + (size_t)(((lane & 7) ^ (bl & 7)) << 4);

  // ---- stage A slab for ci-block s: slab[r=6][c=66][ci=64] bf16, 128B/pos,
  // 16B-slot swizzle: phys_slot = logical_slot ^ (pos&7); linear LDS dest +
  // inverse-swizzled global source (G21).
  auto stageA = [&](int s) {
    const int ci0 = s << 6;
    for (int t = wid; t < 50; t += 8) {
      const int ch = (t << 3) + (lane >> 3);   // pos = r*66+c, 0..399
      const int r  = ch / 66;
      const int c  = ch - r * 66;
      const int ir = ho0 - 1 + r;              // image row
      const int ic = c - 1;                    // image col
      const int k  = (lane & 7) ^ (ch & 7);    // logical 16B slot (8 ci elems)
      const char* src;
      if (ch < 396 && ir >= 0 && ir < 64 && ic >= 0 && ic < 64)
        src = (const char*)(xT + ((((size_t)bb << 6) + ir) * 64 + ic) * 256 + ci0 + (k << 3));
      else
        src = zb + (k << 4);
      gload_lds16(src, lds + (t << 10));
    }
  };

  // ---- stage B tile (exactly 4 loads per wave): Btile[co=256][ci=64] bf16
  auto stageB = [&](int bi, int phOff /*bytes: (tap*256+s*64)*2*/) {
    char* buf = lds + A_BYTES + bi * B_BYTES;
    const char* wsrc = (const char*)Wt + bsrcLane + phOff;
#pragma unroll
    for (int it = 0; it < 4; ++it) {
      const int t = wid + (it << 3);
      gload_lds16(wsrc + (size_t)t * 36864, buf + (t << 10));
    }
  };

  stageA(0);
  stageB(0, 0);
  asm volatile("s_waitcnt vmcnt(0)" ::: "memory");
  __builtin_amdgcn_s_barrier();
  __builtin_amdgcn_sched_barrier(0);

  int pb = 0;
  for (int s = 0; s < 4; ++s) {
    for (int tap = 0; tap < 9; ++tap) {
      const int p = s * 9 + tap;
      if (p > 0) {
        __builtin_amdgcn_s_barrier();          // (A): prev readers of buf[pb^1] done
        __builtin_amdgcn_sched_barrier(0);
      }
      if (p + 1 < 36) {
        int ntap = tap + 1, ns = s;
        if (ntap == 9) { ntap = 0; ++ns; }
        stageB(pb ^ 1, ((ntap << 8) + (ns << 6)) << 1);
        asm volatile("s_waitcnt vmcnt(4)" ::: "memory");  // cur stage done; next in flight
      } else {
        asm volatile("s_waitcnt vmcnt(0)" ::: "memory");
      }
      __builtin_amdgcn_sched_barrier(0);
      __builtin_amdgcn_s_barrier();            // (B): everyone's cur stage landed
      __builtin_amdgcn_sched_barrier(0);

      const int dh = (tap >= 6) ? 2 : (tap >= 3 ? 1 : 0);
      const int dw = tap - dh * 3;
      const char* Bb = lds + A_BYTES + pb * B_BYTES;
      __builtin_amdgcn_s_setprio(1);
#pragma unroll
      for (int kk = 0; kk < 2; ++kk) {
        const int ci_off = (kk << 5) + ((lane >> 4) << 3);
        bf16x8 av[8];
#pragma unroll
        for (int i = 0; i < 8; ++i) {
          const int pos = ((wr << 1) + (i >> 2) + dh) * 66 + ((i & 3) << 4) + (lane & 15) + dw;
          const int off = ((pos << 7) + (ci_off << 1)) ^ ((pos & 7) << 4);
          av[i] = *(const bf16x8*)(lds + off);
        }
#pragma unroll
        for (int j = 0; j < 4; ++j) {
          const bf16x8 bv = *(const bf16x8*)(Bb + boff[j][kk]);
#pragma unroll
          for (int i = 0; i < 8; ++i)
            acc[i][j] = __builtin_amdgcn_mfma_f32_16x16x32_bf16(av[i], bv, acc[i][j], 0, 0, 0);
        }
      }
      __builtin_amdgcn_s_setprio(0);

      if (tap == 8 && s < 3) {                 // restage A (single-buffered):
        __builtin_amdgcn_s_barrier();          // all waves done reading A(s)
        __builtin_amdgcn_sched_barrier(0);
        stageA(s + 1);                         // drained by next phase's vmcnt(4)
      }
      pb ^= 1;
    }
  }

  // ---- epilogue: per-wave LDS transpose (coalesced IO) + fused BN stats
  __syncthreads();
  float* sw    = (float*)lds + wid * 2064;     // 16 co x 129 m floats per wave
  float* lstat = (float*)(lds + 100352);       // 512 floats
  if (tid < 512) lstat[tid] = 0.f;
  __syncthreads();

  const int cl = lane & 15, ch4 = (lane >> 4) << 2;
#pragma unroll
  for (int j = 0; j < 4; ++j) {
    asm volatile("s_waitcnt lgkmcnt(0)" ::: "memory");
#pragma unroll
    for (int i = 0; i < 8; ++i)
#pragma unroll
      for (int r = 0; r < 4; ++r)
        sw[cl * 129 + (i << 4) + ch4 + r] = acc[i][j][r];
    for (int cc = 0; cc < 16; ++cc) {
      const int co = (wc << 6) + (j << 4) + cc;
      const float be = beff[co];
      float s1 = 0.f, s2 = 0.f;
#pragma unroll
      for (int half = 0; half < 2; ++half) {
        const float conv = sw[cc * 129 + (half << 6) + lane];
        const int ho = ho0 + (wr << 1) + half;
        const size_t oi = ((((size_t)bb << 8) + (size_t)co) << 12) + (ho << 6) + lane;
        const float v = x[oi] + conv + be;
        out[oi] = v;
        s1 += v; s2 += v * v;
      }
#pragma unroll
      for (int o = 1; o < 64; o <<= 1) {
        s1 += __shfl_xor(s1, o);
        s2 += __shfl_xor(s2, o);
      }
      if (lane == 0) {
        atomicAdd(&lstat[co], s1);
        atomicAdd(&lstat[256 + co], s2);
      }
    }
  }
  __syncthreads();
  if (tid < 512) atomicAdd(&statsG[tid], lstat[tid]);
}

// K2b: finalize BN scale/shift from global sums
__global__ void k_finalize(const float* __restrict__ statsG, const float* __restrict__ gamma,
                           const float* __restrict__ beta, float* __restrict__ scale,
                           float* __restrict__ shift) {
  const int co = threadIdx.x;    // 256
  const float mean = statsG[co] * (1.f / 65536.f);
  const float var  = statsG[256 + co] * (1.f / 65536.f) - mean * mean;
  const float inv  = rsqrtf(var + 1e-5f);
  const float sc   = gamma[co] * inv;
  scale[co] = sc;
  shift[co] = beta[co] - mean * sc;
}

// K3: in-place BN apply
__global__ void k_apply(float* __restrict__ out, const float* __restrict__ scale,
                        const float* __restrict__ shift) {
  size_t i = (size_t)blockIdx.x * 256 + threadIdx.x;   // float4 index
  float4* p = (float4*)out;
  float4 v = p[i];
  int co = (int)((i >> 10) & 255);
  float sc = scale[co], sh = shift[co];
  v.x = v.x * sc + sh; v.y = v.y * sc + sh; v.z = v.z * sc + sh; v.w = v.w * sc + sh;
  p[i] = v;
}

extern "C" void kernel_launch(void* const* d_in, const int* in_sizes, int n_in,
                              void* d_out, int out_size, void* d_ws, size_t ws_size,
                              hipStream_t stream) {
  const float* x     = (const float*)d_in[0];
  const float* wall  = (const float*)d_in[1];
  const float* bias  = (const float*)d_in[2];
  const float* alpha = (const float*)d_in[3];
  const float* gamma = (const float*)d_in[4];
  const float* beta  = (const float*)d_in[5];
  float* out = (float*)d_out;

  char* ws = (char*)d_ws;
  __bf16* xT     = (__bf16*)(ws + XT_OFF);
  __bf16* Wt     = (__bf16*)(ws + WT_OFF);
  float*  beff   = (float*)(ws + BEFF_OFF);
  float*  scale  = (float*)(ws + SCALE_OFF);
  float*  shift  = (float*)(ws + SHIFT_OFF);
  float*  zerob  = (float*)(ws + ZERO_OFF);
  float*  statsG = (float*)(ws + STATS_OFF);

  k_wred<<<256, 256, 0, stream>>>(wall, bias, alpha, Wt, beff, zerob, statsG);
  k_xpose<<<1024, 256, 0, stream>>>(x, xT);
  k_conv<<<256, 512, 0, stream>>>(x, xT, Wt, beff, (const __bf16*)zerob, out, statsG);
  k_finalize<<<1, 256, 0, stream>>>(statsG, gamma, beta, scale, shift);
  k_apply<<<16384, 256, 0, stream>>>(out, scale, shift);
}

// Round 4
// 128.960 us; speedup vs baseline: 2.0499x; 1.1939x over previous
//
#include <hip/hip_runtime.h>
#include <stdint.h>

typedef __attribute__((__ext_vector_type__(8))) __bf16 bf16x8;
typedef __attribute__((__ext_vector_type__(4))) float  f32x4;

// ---- workspace layout (bytes) ----
#define XT_OFF    0ul          // 16*64*64*256 bf16 = 33,554,432
#define WT_OFF    33554432ul   // 256*9*256 bf16    =  1,179,648
#define BEFF_OFF  34734080ul   // 256 f32
#define ZERO_OFF  34737152ul   // 256 B zeros
#define STATS_OFF 34737408ul   // 512 f32 (sum, sumsq per channel)

__device__ inline void gload_lds16(const void* g, void* l) {
  __builtin_amdgcn_global_load_lds((const __attribute__((address_space(1))) void*)g,
                                   (__attribute__((address_space(3))) void*)l,
                                   16, 0, 0);
}

// K1: W_t[co][tap][ci] = alpha/16 * sum_{r,o} weight_all[r*256+co][o*256+ci][tap]
__global__ void k_wred(const float* __restrict__ w, const float* __restrict__ bias,
                       const float* __restrict__ alpha_p, __bf16* __restrict__ Wt,
                       float* __restrict__ beff, float* __restrict__ zerob,
                       float* __restrict__ statsG) {
  const int co = blockIdx.x;    // 256
  const int ci = threadIdx.x;   // 256
  float a[9];
#pragma unroll
  for (int t = 0; t < 9; ++t) a[t] = 0.f;
#pragma unroll
  for (int r = 0; r < 2; ++r)
#pragma unroll
    for (int o = 0; o < 8; ++o) {
      const float* p = w + ((size_t)(r * 256 + co) * 2048 + (size_t)(o * 256 + ci)) * 9;
#pragma unroll
      for (int t = 0; t < 9; ++t) a[t] += p[t];
    }
  const float sc = alpha_p[0] * 0.0625f;      // alpha / (NORI*NROT)
#pragma unroll
  for (int t = 0; t < 9; ++t)
    Wt[((size_t)co * 9 + t) * 256 + ci] = (__bf16)(a[t] * sc);
  if (ci == 0) beff[co] = (bias[co] + bias[256 + co]) * 8.0f * sc;
  if (blockIdx.x == 0) {
    statsG[ci] = 0.f; statsG[256 + ci] = 0.f;
    if (ci < 64) zerob[ci] = 0.f;
  }
}

// K1b: x[b][ci][h][w] f32 -> xT[b][h][w][ci] bf16  (LDS-tiled transpose)
__global__ void k_xpose(const float* __restrict__ x, __bf16* __restrict__ xT) {
  __shared__ __bf16 lds[64 * 258];
  int bh = blockIdx.x;          // 16*64
  int b = bh >> 6, h = bh & 63;
  int t = threadIdx.x;          // 256
  int w = t & 63, cg = t >> 6;
  const float* xb = x + ((size_t)b * 16384 + h) * 64;   // + ci*4096 + w
#pragma unroll 4
  for (int cb = 0; cb < 256; cb += 4) {
    int ci = cb + cg;
    lds[w * 258 + ci] = (__bf16)xb[(size_t)ci * 4096 + w];
  }
  __syncthreads();
  const uint32_t* l32 = (const uint32_t*)lds;
  uint32_t* o32 = (uint32_t*)(xT + ((size_t)b * 64 + h) * 64 * 256);
  int c2 = t & 127, wg = t >> 7;              // 2 w per iter
  for (int w0 = 0; w0 < 64; w0 += 2) {
    int ww = w0 + wg;
    o32[ww * 128 + c2] = l32[ww * 129 + c2];
  }
}

// K2: implicit-GEMM conv + residual + fused BN stats.
// 256 blocks (1/CU), 1024 threads = 16 waves (4m x 4n) -> 4 waves/SIMD.
// BM=256 (4 out rows x 64 w), N=256 co, 36 phases = s(4 ci64) x tap(9).
// R2-style phase (compiler-scheduled): stageB(next) issue -> MFMA -> syncthreads.
// Wave tile 64x64: acc[4][4] f32x4 (64 VGPR).
#define A_BYTES 51200            // 50 chunks * 1024 (396 pos * 128B, padded)
#define B_BYTES 32768

__global__ __launch_bounds__(1024) void k_conv(
    const float* __restrict__ x, const __bf16* __restrict__ xT,
    const __bf16* __restrict__ Wt, const float* __restrict__ beff,
    const __bf16* __restrict__ zerob, float* __restrict__ out,
    float* __restrict__ statsG)
{
  __shared__ __align__(16) char lds[A_BYTES + 2 * B_BYTES];   // 116736 B
  const int bb   = blockIdx.x >> 4;
  const int ho0  = (blockIdx.x & 15) << 2;   // 4 output rows per block
  const int tid  = threadIdx.x;
  const int lane = tid & 63;
  const int wid  = tid >> 6;                 // 16 waves: 4 (m) x 4 (co)
  const int wr   = wid >> 2;                 // image row ho0+wr
  const int wc   = wid & 3;                  // co quarter (64)

  f32x4 acc[4][4];
#pragma unroll
  for (int i = 0; i < 4; ++i)
#pragma unroll
    for (int j = 0; j < 4; ++j)
#pragma unroll
      for (int r = 0; r < 4; ++r) acc[i][j][r] = 0.f;

  const char* zb = (const char*)zerob;

  // hoisted B ds_read byte offsets (constant across phases)
  int boff[4][2];
#pragma unroll
  for (int j = 0; j < 4; ++j)
#pragma unroll
    for (int kk = 0; kk < 2; ++kk) {
      const int co     = (wc << 6) + (j << 4) + (lane & 15);
      const int ci_off = (kk << 5) + ((lane >> 4) << 3);
      boff[j][kk] = ((co << 7) + (ci_off << 1)) ^ ((co & 7) << 4);
    }
  // hoisted B stage per-lane source offset (bytes): co = t*8 + (lane>>3)
  const int bl = lane >> 3;
  const size_t bsrcLane = (size_t)bl * 4608 + (size_t)(((lane & 7) ^ (bl & 7)) << 4);

  // ---- stage A slab for ci-block s: slab[r=6][c=66][ci=64] bf16, 128B/pos.
  // 16B-slot swizzle: phys_slot = logical_slot ^ (pos&7); linear LDS dest +
  // inverse-swizzled global source (G21).
  auto stageA = [&](int s) {
    const int ci0 = s << 6;
    for (int t = wid; t < 50; t += 16) {
      const int ch = (t << 3) + (lane >> 3);   // pos = r*66+c, 0..399
      const int r  = ch / 66;
      const int c  = ch - r * 66;
      const int ir = ho0 - 1 + r;              // image row
      const int ic = c - 1;                    // image col
      const int k  = (lane & 7) ^ (ch & 7);    // logical 16B slot (8 ci elems)
      const char* src;
      if (ch < 396 && ir >= 0 && ir < 64 && ic >= 0 && ic < 64)
        src = (const char*)(xT + ((((size_t)bb << 6) + ir) * 64 + ic) * 256 + ci0 + (k << 3));
      else
        src = zb + (k << 4);
      gload_lds16(src, lds + (t << 10));
    }
  };

  // ---- stage B tile (2 loads per wave): Btile[co=256][ci=64] bf16
  auto stageB = [&](int bi, int phOff /*bytes: (tap*256+s*64)*2*/) {
    char* buf = lds + A_BYTES + bi * B_BYTES;
    const char* wsrc = (const char*)Wt + bsrcLane + phOff;
    gload_lds16(wsrc + (size_t)wid * 36864, buf + (wid << 10));
    gload_lds16(wsrc + (size_t)(wid + 16) * 36864, buf + ((wid + 16) << 10));
  };

  stageA(0);
  stageB(0, 0);
  __syncthreads();

  int pb = 0;
  for (int s = 0; s < 4; ++s) {
    for (int tap = 0; tap < 9; ++tap) {
      const int p = s * 9 + tap;
      if (p + 1 < 36) {
        int ntap = tap + 1, ns = s;
        if (ntap == 9) { ntap = 0; ++ns; }
        stageB(pb ^ 1, ((ntap << 8) + (ns << 6)) << 1);
      }
      const int dh = (tap >= 6) ? 2 : (tap >= 3 ? 1 : 0);
      const int dw = tap - dh * 3;
      const char* Bb = lds + A_BYTES + pb * B_BYTES;
      __builtin_amdgcn_s_setprio(1);
#pragma unroll
      for (int kk = 0; kk < 2; ++kk) {
        const int ci_off = (kk << 5) + ((lane >> 4) << 3);
        bf16x8 av[4];
#pragma unroll
        for (int i = 0; i < 4; ++i) {
          const int pos = (wr + dh) * 66 + (i << 4) + (lane & 15) + dw;
          const int off = ((pos << 7) + (ci_off << 1)) ^ ((pos & 7) << 4);
          av[i] = *(const bf16x8*)(lds + off);
        }
#pragma unroll
        for (int j = 0; j < 4; ++j) {
          const bf16x8 bv = *(const bf16x8*)(Bb + boff[j][kk]);
#pragma unroll
          for (int i = 0; i < 4; ++i)
            acc[i][j] = __builtin_amdgcn_mfma_f32_16x16x32_bf16(av[i], bv, acc[i][j], 0, 0, 0);
        }
      }
      __builtin_amdgcn_s_setprio(0);
      __syncthreads();                         // drains this phase's staging
      if (tap == 8 && s < 3) {                 // restage A (single-buffered)
        stageA(s + 1);
        __syncthreads();
      }
      pb ^= 1;
    }
  }

  // ---- epilogue: per-wave LDS transpose (coalesced IO) + fused BN stats
  __syncthreads();
  float* sw    = (float*)lds + wid * 1040;     // 16 co x 65 floats per wave
  float* lstat = (float*)(lds + 112640);       // 512 floats
  if (tid < 512) lstat[tid] = 0.f;
  __syncthreads();

  const int cl = lane & 15, ch4 = (lane >> 4) << 2;
  const int ho = ho0 + wr;
  const int cc2 = lane >> 2, q = lane & 3;     // reduction roles
#pragma unroll
  for (int j = 0; j < 4; ++j) {
    asm volatile("s_waitcnt lgkmcnt(0)" ::: "memory");
#pragma unroll
    for (int i = 0; i < 4; ++i)
#pragma unroll
      for (int r = 0; r < 4; ++r)
        sw[cl * 65 + (i << 4) + ch4 + r] = acc[i][j][r];
    asm volatile("s_waitcnt lgkmcnt(0)" ::: "memory");
    for (int cc = 0; cc < 16; ++cc) {
      const int co = (wc << 6) + (j << 4) + cc;
      const float conv = sw[cc * 65 + lane];
      const size_t oi = ((((size_t)bb << 8) + (size_t)co) << 12) + (ho << 6) + lane;
      const float v = x[oi] + conv + beff[co];
      out[oi] = v;
      sw[cc * 65 + lane] = v;                  // same addr per lane: no race
    }
    asm volatile("s_waitcnt lgkmcnt(0)" ::: "memory");
    // per-thread partial over 16 w values of one co, then 2-level shfl
    float r1 = 0.f, r2 = 0.f;
#pragma unroll
    for (int k = 0; k < 16; ++k) {
      const float vv = sw[cc2 * 65 + (q << 4) + k];
      r1 += vv; r2 += vv * vv;
    }
    r1 += __shfl_xor(r1, 1); r2 += __shfl_xor(r2, 1);
    r1 += __shfl_xor(r1, 2); r2 += __shfl_xor(r2, 2);
    if (q == 0) {
      const int co = (wc << 6) + (j << 4) + cc2;
      atomicAdd(&lstat[co], r1);
      atomicAdd(&lstat[256 + co], r2);
    }
    asm volatile("s_waitcnt lgkmcnt(0)" ::: "memory");  // reads done before next j overwrites
  }
  __syncthreads();
  if (tid < 512) atomicAdd(&statsG[tid], lstat[tid]);
}

// K3: BN finalize (inline) + apply
__global__ void k_apply(float* __restrict__ out, const float* __restrict__ statsG,
                        const float* __restrict__ gamma, const float* __restrict__ beta) {
  size_t i = (size_t)blockIdx.x * 256 + threadIdx.x;   // float4 index
  int co = (int)((i >> 10) & 255);
  const float mean = statsG[co] * (1.f / 65536.f);
  const float var  = statsG[256 + co] * (1.f / 65536.f) - mean * mean;
  const float inv  = rsqrtf(var + 1e-5f);
  const float sc   = gamma[co] * inv;
  const float sh   = beta[co] - mean * sc;
  float4* p = (float4*)out;
  float4 v = p[i];
  v.x = v.x * sc + sh; v.y = v.y * sc + sh; v.z = v.z * sc + sh; v.w = v.w * sc + sh;
  p[i] = v;
}

extern "C" void kernel_launch(void* const* d_in, const int* in_sizes, int n_in,
                              void* d_out, int out_size, void* d_ws, size_t ws_size,
                              hipStream_t stream) {
  const float* x     = (const float*)d_in[0];
  const float* wall  = (const float*)d_in[1];
  const float* bias  = (const float*)d_in[2];
  const float* alpha = (const float*)d_in[3];
  const float* gamma = (const float*)d_in[4];
  const float* beta  = (const float*)d_in[5];
  float* out = (float*)d_out;

  char* ws = (char*)d_ws;
  __bf16* xT     = (__bf16*)(ws + XT_OFF);
  __bf16* Wt     = (__bf16*)(ws + WT_OFF);
  float*  beff   = (float*)(ws + BEFF_OFF);
  float*  zerob  = (float*)(ws + ZERO_OFF);
  float*  statsG = (float*)(ws + STATS_OFF);

  k_wred<<<256, 256, 0, stream>>>(wall, bias, alpha, Wt, beff, zerob, statsG);
  k_xpose<<<1024, 256, 0, stream>>>(x, xT);
  k_conv<<<256, 1024, 0, stream>>>(x, xT, Wt, beff, (const __bf16*)zerob, out, statsG);
  k_apply<<<16384, 256, 0, stream>>>(out, statsG, gamma, beta);
}